// Round 8
// baseline (134.650 us; speedup 1.0000x reference)
//
#include <hip/hip_runtime.h>
#include <hip/hip_fp16.h>
#include <math.h>
#include <stdint.h>

namespace {

constexpr int Bsz   = 16384;
constexpr int T     = 200;
constexpr int F     = 4;
constexpr int H     = 10;
constexpr int HP    = 16;   // FC LDS padding: 16 slots/step
constexpr int BLOCK = 256;

// tanh(x) = 1 - 2/(exp(2x)+1); saturates correctly to +/-1 for |x| large.
__device__ __forceinline__ float fast_tanh(float x) {
  float e = exp2f(x * 2.8853900817779268f);   // exp(2x) via v_exp_f32
  return 1.0f - 2.0f * __builtin_amdgcn_rcpf(e + 1.0f);
}

__device__ __forceinline__ float fast_sigmoid(float x) {
  float e = exp2f(x * -1.4426950408889634f);  // exp(-x)
  return __builtin_amdgcn_rcpf(1.0f + e);
}

// quad_perm broadcast: every lane gets ITS OWN quad's lane-J value. VALU rate.
template <int J>
__device__ __forceinline__ float qb(float v) {
  return __int_as_float(__builtin_amdgcn_mov_dpp(
      __float_as_int(v), J * 0x55, 0xF, 0xF, true));
}

// row_half_mirror (0x141): lane i <-> 7-i within each 8-lane half-row ->
// fetches the OTHER quad's (quad-uniform) value. VALU rate.
__device__ __forceinline__ float mir8(float v) {
  return __int_as_float(__builtin_amdgcn_mov_dpp(
      __float_as_int(v), 0x141, 0xF, 0xF, true));
}

#define PIN(v) asm volatile("" : "+v"(v))

// ---- f16-packed weights + v_fma_mix_f32: f16 weight half-word * f32 h,
// accumulated in f32. Halves weight VGPR footprint (72 -> 38) to get the
// live set under the allocator's ~85-reg spill threshold (rounds 4-6:
// AGPR-copy spills = ~500 extra VALU cyc/step). Accumulation stays fp32.
__device__ __forceinline__ void mix_lo(float& s, uint32_t wpk, float h) {
  asm("v_fma_mix_f32 %0, %1, %2, %0 op_sel_hi:[1,0,0]"
      : "+v"(s) : "v"(wpk), "v"(h));
}
__device__ __forceinline__ void mix_hi(float& s, uint32_t wpk, float h) {
  asm("v_fma_mix_f32 %0, %1, %2, %0 op_sel:[1,0,0] op_sel_hi:[1,0,0]"
      : "+v"(s) : "v"(wpk), "v"(h));
}
// both operands f16-packed (weight pair * x pair)
__device__ __forceinline__ void mix2_lo(float& s, uint32_t wpk, uint32_t xpk) {
  asm("v_fma_mix_f32 %0, %1, %2, %0 op_sel_hi:[1,1,0]"
      : "+v"(s) : "v"(wpk), "v"(xpk));
}
__device__ __forceinline__ void mix2_hi(float& s, uint32_t wpk, uint32_t xpk) {
  asm("v_fma_mix_f32 %0, %1, %2, %0 op_sel:[1,1,0] op_sel_hi:[1,1,0]"
      : "+v"(s) : "v"(wpk), "v"(xpk));
}

// pack two f32 -> f16x2 (RNE, init-time only)
__device__ __forceinline__ uint32_t pkh(float a, float b) {
  return (uint32_t)__half_as_ushort(__float2half(a)) |
         ((uint32_t)__half_as_ushort(__float2half(b)) << 16);
}
// pack two f32 -> f16x2 (RTZ, one v_cvt_pkrtz — used per-step for x)
__device__ __forceinline__ uint32_t pkrtz(float a, float b) {
  auto p = __builtin_amdgcn_cvt_pkrtz(a, b);  // __fp16 ext_vector_type(2)
  return __builtin_bit_cast(uint32_t, p);
}

__global__ __launch_bounds__(BLOCK, 2) void rnn2_mix(
    const float* __restrict__ x,
    const float* __restrict__ W_ih0, const float* __restrict__ W_hh0,
    const float* __restrict__ b_ih0, const float* __restrict__ b_hh0,
    const float* __restrict__ W_ih1, const float* __restrict__ W_hh1,
    const float* __restrict__ b_ih1, const float* __restrict__ b_hh1,
    const float* __restrict__ W_fc, const float* __restrict__ b_fc,
    float* __restrict__ out) {
  __shared__ float s_wfc[T * HP];
  for (int i = threadIdx.x; i < T * HP; i += BLOCK) {
    int t = i >> 4, u = i & 15;
    s_wfc[i] = (u < H) ? W_fc[t * H + u] : 0.0f;
  }
  __syncthreads();

  const int g  = blockIdx.x * BLOCK + threadIdx.x;
  const int b  = g >> 3;                  // batch element
  const int r  = g & 7;                   // sub-lane in 8-group
  const int qp = (threadIdx.x >> 2) & 1;  // quad parity in the 8-group
  const int uA = r;                       // first unit (r<=7<10, always real)
  const int uB = 8 + r;                   // second unit (real only r<2)
  const bool vB = (uB < H);

  // pack a 10-wide weight row into 5 f16x2 regs in own/other/hi order:
  // {(ow0,ow1),(ow2,ow3),(ot0,ot1),(ot2,ot3),(u8,u9)}
  auto pack10 = [&](uint32_t* d, const float* W, int u, bool valid) {
    float v[10];
#pragma unroll
    for (int j = 0; j < 10; ++j) v[j] = valid ? W[u * H + j] : 0.0f;
    const int ow = qp * 4, ot = 4 - qp * 4;
    d[0] = pkh(v[ow + 0], v[ow + 1]);
    d[1] = pkh(v[ow + 2], v[ow + 3]);
    d[2] = pkh(v[ot + 0], v[ot + 1]);
    d[3] = pkh(v[ot + 2], v[ot + 3]);
    d[4] = pkh(v[8], v[9]);
  };

  uint32_t wh0A[5], wh0B[5], wi1A[5], wi1B[5], wh1A[5], wh1B[5];
  pack10(wh0A, W_hh0, uA, true);  pack10(wh0B, W_hh0, uB, vB);
  pack10(wi1A, W_ih1, uA, true);  pack10(wi1B, W_ih1, uB, vB);
  pack10(wh1A, W_hh1, uA, true);  pack10(wh1B, W_hh1, uB, vB);
  uint32_t wi0A[2], wi0B[2];
  wi0A[0] = pkh(W_ih0[uA * F + 0], W_ih0[uA * F + 1]);
  wi0A[1] = pkh(W_ih0[uA * F + 2], W_ih0[uA * F + 3]);
  wi0B[0] = vB ? pkh(W_ih0[uB * F + 0], W_ih0[uB * F + 1]) : 0u;
  wi0B[1] = vB ? pkh(W_ih0[uB * F + 2], W_ih0[uB * F + 3]) : 0u;
  float bA0 = b_ih0[uA] + b_hh0[uA];
  float bB0 = vB ? (b_ih0[uB] + b_hh0[uB]) : 0.0f;
  float bA1 = b_ih1[uA] + b_hh1[uA];
  float bB1 = vB ? (b_ih1[uB] + b_hh1[uB]) : 0.0f;

#pragma unroll
  for (int k = 0; k < 5; ++k) {
    PIN(wh0A[k]); PIN(wh0B[k]); PIN(wi1A[k]);
    PIN(wi1B[k]); PIN(wh1A[k]); PIN(wh1B[k]);
  }
  PIN(wi0A[0]); PIN(wi0A[1]); PIN(wi0B[0]); PIN(wi0B[1]);
  PIN(bA0); PIN(bB0); PIN(bA1); PIN(bB1);

  const float4* __restrict__ xrow =
      reinterpret_cast<const float4*>(x + (size_t)b * (T * F));

  float h0ow[4] = {0, 0, 0, 0}, h0ot[4] = {0, 0, 0, 0}, h0hi[2] = {0, 0};
  float h1ow[4] = {0, 0, 0, 0}, h1ot[4] = {0, 0, 0, 0}, h1hi[2] = {0, 0};
  float acc = 0.0f;

  float4 x0 = xrow[0];
  uint32_t xpk0 = pkrtz(x0.x, x0.y), xpk1 = pkrtz(x0.z, x0.w);

#pragma unroll 1
  for (int t = 0; t < T; ++t) {
    float4 xn = xrow[(t + 1 < T) ? t + 1 : t];  // software prefetch
    float fA = s_wfc[t * HP + uA];
    float fB = s_wfc[t * HP + uB];

    // ---- layer 0 ----  (split chains sA/pA for ILP)
    float sA = bA0, sB = bB0, pA = 0.0f, pB = 0.0f;
    mix2_lo(sA, wi0A[0], xpk0); mix2_hi(sA, wi0A[0], xpk0);
    mix2_lo(sB, wi0B[0], xpk0); mix2_hi(sB, wi0B[0], xpk0);
    mix2_lo(sA, wi0A[1], xpk1); mix2_hi(sA, wi0A[1], xpk1);
    mix2_lo(sB, wi0B[1], xpk1); mix2_hi(sB, wi0B[1], xpk1);
    mix_lo(pA, wh0A[0], h0ow[0]); mix_hi(pA, wh0A[0], h0ow[1]);
    mix_lo(pB, wh0B[0], h0ow[0]); mix_hi(pB, wh0B[0], h0ow[1]);
    mix_lo(pA, wh0A[1], h0ow[2]); mix_hi(pA, wh0A[1], h0ow[3]);
    mix_lo(pB, wh0B[1], h0ow[2]); mix_hi(pB, wh0B[1], h0ow[3]);
    mix_lo(pA, wh0A[2], h0ot[0]); mix_hi(pA, wh0A[2], h0ot[1]);
    mix_lo(pB, wh0B[2], h0ot[0]); mix_hi(pB, wh0B[2], h0ot[1]);
    mix_lo(pA, wh0A[3], h0ot[2]); mix_hi(pA, wh0A[3], h0ot[3]);
    mix_lo(pB, wh0B[3], h0ot[2]); mix_hi(pB, wh0B[3], h0ot[3]);
    mix_lo(pA, wh0A[4], h0hi[0]); mix_hi(pA, wh0A[4], h0hi[1]);
    mix_lo(pB, wh0B[4], h0hi[0]); mix_hi(pB, wh0B[4], h0hi[1]);
    float mA = fast_tanh(sA + pA);
    float mB = fast_tanh(sB + pB);   // pad lanes: tanh(0) = 0 exactly

    // exchange new h0 across the 8-group (pure DPP)
    h0ow[0] = qb<0>(mA); h0ot[0] = mir8(h0ow[0]);
    h0ow[1] = qb<1>(mA); h0ot[1] = mir8(h0ow[1]);
    h0ow[2] = qb<2>(mA); h0ot[2] = mir8(h0ow[2]);
    h0ow[3] = qb<3>(mA); h0ot[3] = mir8(h0ow[3]);
    { float u8 = qb<0>(mB); h0hi[0] = u8 + mir8(u8);   // other quad holds 0
      float u9 = qb<1>(mB); h0hi[1] = u9 + mir8(u9); }

    // ---- layer 1 ----
    sA = bA1; sB = bB1; pA = 0.0f; pB = 0.0f;
    mix_lo(sA, wi1A[0], h0ow[0]); mix_hi(sA, wi1A[0], h0ow[1]);
    mix_lo(sB, wi1B[0], h0ow[0]); mix_hi(sB, wi1B[0], h0ow[1]);
    mix_lo(sA, wi1A[1], h0ow[2]); mix_hi(sA, wi1A[1], h0ow[3]);
    mix_lo(sB, wi1B[1], h0ow[2]); mix_hi(sB, wi1B[1], h0ow[3]);
    mix_lo(sA, wi1A[2], h0ot[0]); mix_hi(sA, wi1A[2], h0ot[1]);
    mix_lo(sB, wi1B[2], h0ot[0]); mix_hi(sB, wi1B[2], h0ot[1]);
    mix_lo(sA, wi1A[3], h0ot[2]); mix_hi(sA, wi1A[3], h0ot[3]);
    mix_lo(sB, wi1B[3], h0ot[2]); mix_hi(sB, wi1B[3], h0ot[3]);
    mix_lo(sA, wi1A[4], h0hi[0]); mix_hi(sA, wi1A[4], h0hi[1]);
    mix_lo(sB, wi1B[4], h0hi[0]); mix_hi(sB, wi1B[4], h0hi[1]);
    mix_lo(pA, wh1A[0], h1ow[0]); mix_hi(pA, wh1A[0], h1ow[1]);
    mix_lo(pB, wh1B[0], h1ow[0]); mix_hi(pB, wh1B[0], h1ow[1]);
    mix_lo(pA, wh1A[1], h1ow[2]); mix_hi(pA, wh1A[1], h1ow[3]);
    mix_lo(pB, wh1B[1], h1ow[2]); mix_hi(pB, wh1B[1], h1ow[3]);
    mix_lo(pA, wh1A[2], h1ot[0]); mix_hi(pA, wh1A[2], h1ot[1]);
    mix_lo(pB, wh1B[2], h1ot[0]); mix_hi(pB, wh1B[2], h1ot[1]);
    mix_lo(pA, wh1A[3], h1ot[2]); mix_hi(pA, wh1A[3], h1ot[3]);
    mix_lo(pB, wh1B[3], h1ot[2]); mix_hi(pB, wh1B[3], h1ot[3]);
    mix_lo(pA, wh1A[4], h1hi[0]); mix_hi(pA, wh1A[4], h1hi[1]);
    mix_lo(pB, wh1B[4], h1hi[0]); mix_hi(pB, wh1B[4], h1hi[1]);
    mA = fast_tanh(sA + pA);
    mB = fast_tanh(sB + pB);

    acc = fmaf(mA, fA, acc);
    acc = fmaf(mB, fB, acc);

    // exchange new h1
    h1ow[0] = qb<0>(mA); h1ot[0] = mir8(h1ow[0]);
    h1ow[1] = qb<1>(mA); h1ot[1] = mir8(h1ow[1]);
    h1ow[2] = qb<2>(mA); h1ot[2] = mir8(h1ow[2]);
    h1ow[3] = qb<3>(mA); h1ot[3] = mir8(h1ow[3]);
    { float u8 = qb<0>(mB); h1hi[0] = u8 + mir8(u8);
      float u9 = qb<1>(mB); h1hi[1] = u9 + mir8(u9); }

    xpk0 = pkrtz(xn.x, xn.y);
    xpk1 = pkrtz(xn.z, xn.w);
  }

  // 8-lane reduce of the FC accumulator
  acc += __shfl_xor(acc, 1);
  acc += __shfl_xor(acc, 2);
  acc += __shfl_xor(acc, 4);
  if (r == 0) out[b] = fast_sigmoid(acc + b_fc[0]);
}

}  // namespace

extern "C" void kernel_launch(void* const* d_in, const int* in_sizes, int n_in,
                              void* d_out, int out_size, void* d_ws, size_t ws_size,
                              hipStream_t stream) {
  const float* x     = (const float*)d_in[0];
  const float* W_ih0 = (const float*)d_in[1];
  const float* W_hh0 = (const float*)d_in[2];
  const float* b_ih0 = (const float*)d_in[3];
  const float* b_hh0 = (const float*)d_in[4];
  const float* W_ih1 = (const float*)d_in[5];
  const float* W_hh1 = (const float*)d_in[6];
  const float* b_ih1 = (const float*)d_in[7];
  const float* b_hh1 = (const float*)d_in[8];
  const float* W_fc  = (const float*)d_in[9];
  const float* b_fc  = (const float*)d_in[10];
  float* out = (float*)d_out;

  dim3 grid((Bsz * 8) / BLOCK), block(BLOCK);
  hipLaunchKernelGGL(rnn2_mix, grid, block, 0, stream,
                     x, W_ih0, W_hh0, b_ih0, b_hh0,
                     W_ih1, W_hh1, b_ih1, b_hh1, W_fc, b_fc, out);
}